// Round 4
// baseline (346.415 us; speedup 1.0000x reference)
//
#include <hip/hip_runtime.h>
#include <hip/hip_bf16.h>
#include <stdint.h>

typedef short short8 __attribute__((ext_vector_type(8)));
typedef float f32x4 __attribute__((ext_vector_type(4)));

#define N_ATOMS 262144
#define NSYM 4
#define NIMG 1024

// ---------- bf16 round-to-nearest-even helpers ----------
__device__ __forceinline__ unsigned short rne_bf16(float f) {
  unsigned int u = __builtin_bit_cast(unsigned int, f);
  unsigned int r = u + 0x7fffu + ((u >> 16) & 1u);
  return (unsigned short)(r >> 16);
}
__device__ __forceinline__ float bf16f(unsigned short h) {
  unsigned int u = ((unsigned int)h) << 16;
  return __builtin_bit_cast(float, u);
}

// ---------- kernel 1: symbol histogram ----------
__global__ void hist_kernel(const int* __restrict__ sym, int* __restrict__ counts, int n) {
  int stride = gridDim.x * blockDim.x;
  int lane = threadIdx.x & 63;
  int c0 = 0, c1 = 0, c2 = 0, c3 = 0;
  for (int i = blockIdx.x * blockDim.x + threadIdx.x; i < n; i += stride) {
    int s = sym[i];
    c0 += (s == 0); c1 += (s == 1); c2 += (s == 2); c3 += (s == 3);
  }
  for (int m = 32; m; m >>= 1) {
    c0 += __shfl_down(c0, m); c1 += __shfl_down(c1, m);
    c2 += __shfl_down(c2, m); c3 += __shfl_down(c3, m);
  }
  if (lane == 0) {
    atomicAdd(&counts[0], c0); atomicAdd(&counts[1], c1);
    atomicAdd(&counts[2], c2); atomicAdd(&counts[3], c3);
  }
}

// ---------- kernel 2: padded offsets (groups aligned to 64) ----------
__global__ void offsets_kernel(const int* __restrict__ counts, int* __restrict__ offs,
                               int* __restrict__ cursors) {
  if (blockIdx.x == 0 && threadIdx.x == 0) {
    int o = 0;
    offs[0] = 0;
    for (int s = 0; s < NSYM; ++s) {
      cursors[s] = o;
      o += (counts[s] + 63) & ~63;
      offs[s + 1] = o;
    }
  }
}

// ---------- kernel 3: scatter atoms into symbol-grouped perm ----------
__global__ void scatter_kernel(const int* __restrict__ sym, int* __restrict__ cursors,
                               int* __restrict__ perm, int n) {
  int i = blockIdx.x * blockDim.x + threadIdx.x;
  int lane = threadIdx.x & 63;
  int wave = threadIdx.x >> 6;
  __shared__ int wcnt[4][NSYM];
  __shared__ int base[NSYM];
  int s = (i < n) ? sym[i] : -1;
  unsigned long long mymask = 0;
  for (int t = 0; t < NSYM; ++t) {
    unsigned long long m = __ballot(s == t);
    if (lane == 0) wcnt[wave][t] = __popcll(m);
    if (s == t) mymask = m;
  }
  __syncthreads();
  if (threadIdx.x < NSYM) {
    int t = threadIdx.x;
    int tot = wcnt[0][t] + wcnt[1][t] + wcnt[2][t] + wcnt[3][t];
    base[t] = atomicAdd(&cursors[t], tot);
  }
  __syncthreads();
  if (s >= 0) {
    int off = base[s];
    for (int w = 0; w < wave; ++w) off += wcnt[w][s];
    off += __popcll(mymask & ((1ull << lane) - 1ull));
    perm[off] = i;
  }
}

// ---------- kernel 4: weights -> transposed bf16 hi/lo planes in ws ----------
// plane t (16384 ushorts): t = layer*4 + s (hi), 8 + layer*4 + s (lo); layout [h][d]
__global__ void wconv_kernel(const float* __restrict__ W1, const float* __restrict__ W2,
                             unsigned short* __restrict__ wt) {
  int idx = blockIdx.x * blockDim.x + threadIdx.x;  // 0..131071
  int layer = idx >> 16;
  int rem = idx & 65535;
  int s = rem >> 14;
  int hd = rem & 16383;
  int h = hd >> 7, d = hd & 127;
  const float* W = layer ? W2 : W1;
  float v = W[(s * 128 + d) * 128 + h];
  unsigned short hi = rne_bf16(v);
  unsigned short lo = rne_bf16(v - bf16f(hi));
  int t = layer * 4 + s;
  wt[t * 16384 + h * 128 + d] = hi;
  wt[(8 + t) * 16384 + h * 128 + d] = lo;
}

// ---------- kernel 5: fused 2-layer MLP via MFMA ----------
// Block = 64 atoms, 4 waves x 16 atoms, no __syncthreads.
// A from global x (in-reg hi/lo split); B from global wt (L2-hot);
// h1 in per-wave LDS: two bf16 planes [16][128], XOR-swizzled. 32KB/block.
__global__ __launch_bounds__(256, 4) void mlp_gemm(
    const float* __restrict__ x, const unsigned short* __restrict__ wt,
    const int* __restrict__ perm, const int* __restrict__ offs,
    const float* __restrict__ b1, const float* __restrict__ b2,
    const float* __restrict__ W3, const float* __restrict__ b3,
    const float* __restrict__ slope, const float* __restrict__ intercept,
    float* __restrict__ e_atom) {
  extern __shared__ char lds[];  // 4 waves x 8KB

  int start = blockIdx.x * 64;
  if (start >= offs[4]) return;
  int s = 0;
  while (s < 3 && start >= offs[s + 1]) ++s;

  int tid = threadIdx.x;
  int wave = tid >> 6, lane = tid & 63;
  int r0 = lane & 15;      // A-row / B-col / C-col selector
  int chunk = lane >> 4;   // k-chunk selector (0..3)
  char* XhB = lds + wave * 8192;        // hi plane [16][256B]
  char* XlB = lds + wave * 8192 + 4096; // lo plane

  const unsigned short* gh1 = wt + (size_t)(0 + s) * 16384;
  const unsigned short* gl1 = wt + (size_t)(8 + s) * 16384;

  int atom = perm[start + wave * 16 + r0];

  // ---- layer-1 A fragments direct from global x, split hi/lo in-register ----
  short8 ah[4], al[4];
  {
    const float* xr = x + (long)(atom < 0 ? 0 : atom) * 128;
    float4 v0[4], v1[4];
#pragma unroll
    for (int k = 0; k < 4; ++k) {
      v0[k] = make_float4(0.f, 0.f, 0.f, 0.f); v1[k] = v0[k];
      if (atom >= 0) {
        v0[k] = *(const float4*)(xr + k * 32 + chunk * 8);
        v1[k] = *(const float4*)(xr + k * 32 + chunk * 8 + 4);
      }
    }
#pragma unroll
    for (int k = 0; k < 4; ++k) {
      float vv[8] = {v0[k].x, v0[k].y, v0[k].z, v0[k].w,
                     v1[k].x, v1[k].y, v1[k].z, v1[k].w};
      unsigned int hw[4], lw[4];
#pragma unroll
      for (int j = 0; j < 4; ++j) {
        unsigned short h0 = rne_bf16(vv[2 * j]), h1 = rne_bf16(vv[2 * j + 1]);
        unsigned short l0 = rne_bf16(vv[2 * j] - bf16f(h0));
        unsigned short l1 = rne_bf16(vv[2 * j + 1] - bf16f(h1));
        hw[j] = (unsigned int)h0 | ((unsigned int)h1 << 16);
        lw[j] = (unsigned int)l0 | ((unsigned int)l1 << 16);
      }
      typedef unsigned int u32x4 __attribute__((ext_vector_type(4)));
      u32x4 hq = {hw[0], hw[1], hw[2], hw[3]};
      u32x4 lq = {lw[0], lw[1], lw[2], lw[3]};
      ah[k] = __builtin_bit_cast(short8, hq);
      al[k] = __builtin_bit_cast(short8, lq);
    }
  }

  // ---- layer 1: acc = X * W1 (3-product hi/lo) ----
  f32x4 zero4 = {0.f, 0.f, 0.f, 0.f};
  f32x4 acc[8];
#pragma unroll
  for (int j = 0; j < 8; ++j) acc[j] = zero4;

#pragma unroll
  for (int cf = 0; cf < 8; ++cf) {
    int brow = (cf * 16 + r0) * 128 + chunk * 8;
    short8 bh[4], bl[4];
#pragma unroll
    for (int k = 0; k < 4; ++k) {
      bh[k] = *(const short8*)(gh1 + brow + k * 32);
      bl[k] = *(const short8*)(gl1 + brow + k * 32);
    }
#pragma unroll
    for (int k = 0; k < 4; ++k) {
      acc[cf] = __builtin_amdgcn_mfma_f32_16x16x32_bf16(ah[k], bh[k], acc[cf], 0, 0, 0);
      acc[cf] = __builtin_amdgcn_mfma_f32_16x16x32_bf16(ah[k], bl[k], acc[cf], 0, 0, 0);
      acc[cf] = __builtin_amdgcn_mfma_f32_16x16x32_bf16(al[k], bh[k], acc[cf], 0, 0, 0);
    }
  }

  // ---- epilogue 1: h1 = relu(acc+b1) -> hi/lo bf16 planes in LDS ----
#pragma unroll
  for (int cf = 0; cf < 8; ++cf) {
    int col = cf * 16 + r0;
    float bias = b1[s * 128 + col];
#pragma unroll
    for (int rr = 0; rr < 4; ++rr) {
      int r = chunk * 4 + rr;
      float v = fmaxf(acc[cf][rr] + bias, 0.f);
      unsigned short h = rne_bf16(v);
      unsigned short l = rne_bf16(v - bf16f(h));
      int off = r * 256 + ((col * 2) ^ ((r & 7) << 4));
      *(unsigned short*)(XhB + off) = h;
      *(unsigned short*)(XlB + off) = l;
    }
  }

  // ---- layer-2 A fragments from per-wave LDS (no barrier) ----
  {
    int xr = (r0 & 7) << 4;
#pragma unroll
    for (int k = 0; k < 4; ++k) {
      int base = r0 * 256 + ((k * 64 + chunk * 16) ^ xr);
      ah[k] = *(const short8*)(XhB + base);
      al[k] = *(const short8*)(XlB + base);
    }
  }

  // ---- layer 2: acc = h1 * W2 ----
  const unsigned short* gh2 = wt + (size_t)(4 + s) * 16384;
  const unsigned short* gl2 = wt + (size_t)(12 + s) * 16384;
#pragma unroll
  for (int j = 0; j < 8; ++j) acc[j] = zero4;

#pragma unroll
  for (int cf = 0; cf < 8; ++cf) {
    int brow = (cf * 16 + r0) * 128 + chunk * 8;
    short8 bh[4], bl[4];
#pragma unroll
    for (int k = 0; k < 4; ++k) {
      bh[k] = *(const short8*)(gh2 + brow + k * 32);
      bl[k] = *(const short8*)(gl2 + brow + k * 32);
    }
#pragma unroll
    for (int k = 0; k < 4; ++k) {
      acc[cf] = __builtin_amdgcn_mfma_f32_16x16x32_bf16(ah[k], bh[k], acc[cf], 0, 0, 0);
      acc[cf] = __builtin_amdgcn_mfma_f32_16x16x32_bf16(ah[k], bl[k], acc[cf], 0, 0, 0);
      acc[cf] = __builtin_amdgcn_mfma_f32_16x16x32_bf16(al[k], bh[k], acc[cf], 0, 0, 0);
    }
  }

  // ---- epilogue 2: e = relu(acc+b2).W3, affine, scatter ----
  float p[4] = {0.f, 0.f, 0.f, 0.f};
#pragma unroll
  for (int cf = 0; cf < 8; ++cf) {
    int col = cf * 16 + r0;
    float b2v = b2[s * 128 + col];
    float w3v = W3[s * 128 + col];
#pragma unroll
    for (int rr = 0; rr < 4; ++rr)
      p[rr] += fmaxf(acc[cf][rr] + b2v, 0.f) * w3v;
  }
#pragma unroll
  for (int m = 1; m < 16; m <<= 1)
#pragma unroll
    for (int rr = 0; rr < 4; ++rr) p[rr] += __shfl_xor(p[rr], m);

  if (r0 == 0) {
    float sl = slope[s], ic = intercept[s], bb = b3[s];
#pragma unroll
    for (int rr = 0; rr < 4; ++rr) {
      int row = wave * 16 + chunk * 4 + rr;
      int a = perm[start + row];
      if (a >= 0) e_atom[a] = sl * (p[rr] + bb) + ic;
    }
  }
}

// ---------- kernel 6: deterministic per-image segment sum ----------
__global__ void segsum_kernel(const float* __restrict__ e_atom, const int* __restrict__ img,
                              float* __restrict__ out, int n) {
  int b = blockIdx.x;
  int lo = 0, hi = n;
  while (lo < hi) { int m = (lo + hi) >> 1; if (img[m] < b) lo = m + 1; else hi = m; }
  int lo2 = lo, hi2 = n;
  while (lo2 < hi2) { int m = (lo2 + hi2) >> 1; if (img[m] < b + 1) lo2 = m + 1; else hi2 = m; }
  float sum = 0.f;
  for (int i = lo + threadIdx.x; i < lo2; i += blockDim.x) sum += e_atom[i];
  for (int m = 32; m; m >>= 1) sum += __shfl_down(sum, m);
  __shared__ float part[4];
  int lane = threadIdx.x & 63, wave = threadIdx.x >> 6;
  if (lane == 0) part[wave] = sum;
  __syncthreads();
  if (threadIdx.x == 0) out[b] = part[0] + part[1] + part[2] + part[3];
}

extern "C" void kernel_launch(void* const* d_in, const int* in_sizes, int n_in,
                              void* d_out, int out_size, void* d_ws, size_t ws_size,
                              hipStream_t stream) {
  const float* x         = (const float*)d_in[0];
  const float* W1        = (const float*)d_in[1];
  const float* b1        = (const float*)d_in[2];
  const float* W2        = (const float*)d_in[3];
  const float* b2        = (const float*)d_in[4];
  const float* W3        = (const float*)d_in[5];
  const float* b3        = (const float*)d_in[6];
  const float* slope     = (const float*)d_in[7];
  const float* intercept = (const float*)d_in[8];
  const int* sym         = (const int*)d_in[9];
  const int* img         = (const int*)d_in[10];

  char* ws = (char*)d_ws;
  int* counts   = (int*)ws;                       // 16 B
  int* cursors  = (int*)(ws + 16);                // 16 B
  int* offs     = (int*)(ws + 32);                // 20 B
  int* perm     = (int*)(ws + 64);                // (N+256)*4
  float* e_atom = (float*)(ws + 64 + 1049600);    // N*4
  unsigned short* wt = (unsigned short*)(ws + 64 + 1049600 + 1048576);  // 512 KB

  hipMemsetAsync(counts, 0, 16, stream);
  hipMemsetAsync(perm, 0xFF, (N_ATOMS + 256) * sizeof(int), stream);

  hist_kernel<<<256, 256, 0, stream>>>(sym, counts, N_ATOMS);
  offsets_kernel<<<1, 64, 0, stream>>>(counts, offs, cursors);
  scatter_kernel<<<N_ATOMS / 256, 256, 0, stream>>>(sym, cursors, perm, N_ATOMS);
  wconv_kernel<<<512, 256, 0, stream>>>(W1, W2, wt);
  mlp_gemm<<<N_ATOMS / 64 + NSYM, 256, 32768, stream>>>(x, wt, perm, offs, b1, b2,
                                                        W3, b3, slope, intercept, e_atom);
  segsum_kernel<<<NIMG, 256, 0, stream>>>(e_atom, img, (float*)d_out, N_ATOMS);
}

// Round 6
// 166.236 us; speedup vs baseline: 2.0839x; 2.0839x over previous
//
#include <hip/hip_runtime.h>
#include <hip/hip_bf16.h>
#include <stdint.h>

typedef short short8 __attribute__((ext_vector_type(8)));
typedef float f32x4 __attribute__((ext_vector_type(4)));
typedef unsigned int u32x4 __attribute__((ext_vector_type(4)));

#define N_ATOMS 262144
#define NSYM 4
#define NIMG 1024

// ---------- bf16 round-to-nearest-even helpers ----------
__device__ __forceinline__ unsigned short rne_bf16(float f) {
  unsigned int u = __builtin_bit_cast(unsigned int, f);
  unsigned int r = u + 0x7fffu + ((u >> 16) & 1u);
  return (unsigned short)(r >> 16);
}
__device__ __forceinline__ float bf16f(unsigned short h) {
  unsigned int u = ((unsigned int)h) << 16;
  return __builtin_bit_cast(float, u);
}

// ---------- kernel 1: symbol histogram ----------
__global__ void hist_kernel(const int* __restrict__ sym, int* __restrict__ counts, int n) {
  int stride = gridDim.x * blockDim.x;
  int lane = threadIdx.x & 63;
  int c0 = 0, c1 = 0, c2 = 0, c3 = 0;
  for (int i = blockIdx.x * blockDim.x + threadIdx.x; i < n; i += stride) {
    int s = sym[i];
    c0 += (s == 0); c1 += (s == 1); c2 += (s == 2); c3 += (s == 3);
  }
  for (int m = 32; m; m >>= 1) {
    c0 += __shfl_down(c0, m); c1 += __shfl_down(c1, m);
    c2 += __shfl_down(c2, m); c3 += __shfl_down(c3, m);
  }
  if (lane == 0) {
    atomicAdd(&counts[0], c0); atomicAdd(&counts[1], c1);
    atomicAdd(&counts[2], c2); atomicAdd(&counts[3], c3);
  }
}

// ---------- kernel 2: padded offsets (groups aligned to 128) ----------
__global__ void offsets_kernel(const int* __restrict__ counts, int* __restrict__ offs,
                               int* __restrict__ cursors) {
  if (blockIdx.x == 0 && threadIdx.x == 0) {
    int o = 0;
    offs[0] = 0;
    for (int s = 0; s < NSYM; ++s) {
      cursors[s] = o;
      o += (counts[s] + 127) & ~127;
      offs[s + 1] = o;
    }
  }
}

// ---------- kernel 3: scatter atoms into symbol-grouped perm ----------
__global__ void scatter_kernel(const int* __restrict__ sym, int* __restrict__ cursors,
                               int* __restrict__ perm, int n) {
  int i = blockIdx.x * blockDim.x + threadIdx.x;
  int lane = threadIdx.x & 63;
  int wave = threadIdx.x >> 6;
  __shared__ int wcnt[4][NSYM];
  __shared__ int base[NSYM];
  int s = (i < n) ? sym[i] : -1;
  unsigned long long mymask = 0;
  for (int t = 0; t < NSYM; ++t) {
    unsigned long long m = __ballot(s == t);
    if (lane == 0) wcnt[wave][t] = __popcll(m);
    if (s == t) mymask = m;
  }
  __syncthreads();
  if (threadIdx.x < NSYM) {
    int t = threadIdx.x;
    int tot = wcnt[0][t] + wcnt[1][t] + wcnt[2][t] + wcnt[3][t];
    base[t] = atomicAdd(&cursors[t], tot);
  }
  __syncthreads();
  if (s >= 0) {
    int off = base[s];
    for (int w = 0; w < wave; ++w) off += wcnt[w][s];
    off += __popcll(mymask & ((1ull << lane) - 1ull));
    perm[off] = i;
  }
}

// ---------- kernel 4: weights -> transposed bf16 hi/lo planes in ws ----------
// plane t (16384 ushorts): t = layer*4 + s (hi), 8 + layer*4 + s (lo); layout [h][d]
__global__ void wconv_kernel(const float* __restrict__ W1, const float* __restrict__ W2,
                             unsigned short* __restrict__ wt) {
  int idx = blockIdx.x * blockDim.x + threadIdx.x;  // 0..131071
  int layer = idx >> 16;
  int rem = idx & 65535;
  int s = rem >> 14;
  int hd = rem & 16383;
  int h = hd >> 7, d = hd & 127;
  const float* W = layer ? W2 : W1;
  float v = W[(s * 128 + d) * 128 + h];
  unsigned short hi = rne_bf16(v);
  unsigned short lo = rne_bf16(v - bf16f(hi));
  int t = layer * 4 + s;
  wt[t * 16384 + h * 128 + d] = hi;
  wt[(8 + t) * 16384 + h * 128 + d] = lo;
}

// ---------- kernel 5: fused 2-layer MLP, weights LDS-stationary ----------
// Block = 4 waves x 32 atoms = 128 atoms. LDS = 64KB: one layer's W hi+lo,
// XOR-swizzled. Layer-phased: stage W1 -> layer1 -> bounce h1 (aliased in Wbuf,
// wave-private 16KB: 32 rows x 512B packed u32) -> stage W2 -> layer2.
__global__ __launch_bounds__(256, 2) void mlp_gemm(
    const float* __restrict__ x, const unsigned short* __restrict__ wt,
    const int* __restrict__ perm, const int* __restrict__ offs,
    const float* __restrict__ b1, const float* __restrict__ b2,
    const float* __restrict__ W3, const float* __restrict__ b3,
    const float* __restrict__ slope, const float* __restrict__ intercept,
    float* __restrict__ e_atom) {
  extern __shared__ char lds[];  // 64 KB: hi plane [0,32K), lo plane [32K,64K)

  int start = blockIdx.x * 128;
  if (start >= offs[4]) return;
  int s = 0;
  while (s < 3 && start >= offs[s + 1]) ++s;

  int tid = threadIdx.x;
  int wave = tid >> 6, lane = tid & 63;
  int r0 = lane & 15;      // A-row / B-col selector
  int chunk = lane >> 4;   // k-chunk selector (0..3)

  const unsigned short* gh1 = wt + (size_t)(0 + s) * 16384;
  const unsigned short* gl1 = wt + (size_t)(8 + s) * 16384;
  const unsigned short* gh2 = wt + (size_t)(4 + s) * 16384;
  const unsigned short* gl2 = wt + (size_t)(12 + s) * 16384;

  // ---- stage W1 into LDS (swizzled: granule gg -> gg ^ (row&7)) ----
#pragma unroll
  for (int it = 0; it < 16; ++it) {
    int c = it * 256 + tid;          // 0..4095 granules (2 planes x 2048)
    int plane = c >> 11;
    int g = c & 2047;
    int row = g >> 4, gg = g & 15;
    const unsigned short* src = (plane ? gl1 : gh1) + row * 128 + gg * 8;
    short8 v = *(const short8*)src;
    *(short8*)(lds + plane * 32768 + row * 256 + ((gg * 16) ^ ((row & 7) << 4))) = v;
  }

  // ---- layer-1 A fragments direct from global x (32 atoms, hi/lo split) ----
  int a0 = perm[start + wave * 32 + r0];
  int a1 = perm[start + wave * 32 + 16 + r0];
  short8 ah[8], al[8];  // f = rf*4 + k
#pragma unroll
  for (int rf = 0; rf < 2; ++rf) {
    int atom = rf ? a1 : a0;
    const float* xr = x + (long)(atom < 0 ? 0 : atom) * 128;
#pragma unroll
    for (int k = 0; k < 4; ++k) {
      float4 v0 = make_float4(0.f, 0.f, 0.f, 0.f), v1 = v0;
      if (atom >= 0) {
        v0 = *(const float4*)(xr + k * 32 + chunk * 8);
        v1 = *(const float4*)(xr + k * 32 + chunk * 8 + 4);
      }
      float vv[8] = {v0.x, v0.y, v0.z, v0.w, v1.x, v1.y, v1.z, v1.w};
      unsigned int hw[4], lw[4];
#pragma unroll
      for (int j = 0; j < 4; ++j) {
        unsigned short h0 = rne_bf16(vv[2 * j]), h1 = rne_bf16(vv[2 * j + 1]);
        unsigned short l0 = rne_bf16(vv[2 * j] - bf16f(h0));
        unsigned short l1 = rne_bf16(vv[2 * j + 1] - bf16f(h1));
        hw[j] = (unsigned int)h0 | ((unsigned int)h1 << 16);
        lw[j] = (unsigned int)l0 | ((unsigned int)l1 << 16);
      }
      u32x4 hq = {hw[0], hw[1], hw[2], hw[3]};
      u32x4 lq = {lw[0], lw[1], lw[2], lw[3]};
      ah[rf * 4 + k] = __builtin_bit_cast(short8, hq);
      al[rf * 4 + k] = __builtin_bit_cast(short8, lq);
    }
  }

  __syncthreads();  // W1 staged

  // ---- layer 1: acc = X * W1 (3-product hi/lo), B from LDS ----
  f32x4 zero4 = {0.f, 0.f, 0.f, 0.f};
  f32x4 acc[2][8];
#pragma unroll
  for (int i = 0; i < 2; ++i)
#pragma unroll
    for (int j = 0; j < 8; ++j) acc[i][j] = zero4;

#pragma unroll
  for (int cf = 0; cf < 8; ++cf) {
    int row = cf * 16 + r0;
    int rbase = row * 256;
    int xr = (row & 7) << 4;
    short8 bh[4], bl[4];
#pragma unroll
    for (int k = 0; k < 4; ++k) {
      int off = rbase + (((k * 4 + chunk) * 16) ^ xr);
      bh[k] = *(const short8*)(lds + off);
      bl[k] = *(const short8*)(lds + 32768 + off);
    }
#pragma unroll
    for (int k = 0; k < 4; ++k)
#pragma unroll
      for (int rf = 0; rf < 2; ++rf) {
        int f = rf * 4 + k;
        acc[rf][cf] = __builtin_amdgcn_mfma_f32_16x16x32_bf16(ah[f], bh[k], acc[rf][cf], 0, 0, 0);
        acc[rf][cf] = __builtin_amdgcn_mfma_f32_16x16x32_bf16(ah[f], bl[k], acc[rf][cf], 0, 0, 0);
        acc[rf][cf] = __builtin_amdgcn_mfma_f32_16x16x32_bf16(al[f], bh[k], acc[rf][cf], 0, 0, 0);
      }
  }

  __syncthreads();  // all waves done reading W1 -> Wbuf reusable as bounce

  // ---- epilogue 1: h1 = relu(acc+b1) -> wave-private bounce ----
  // bounce: 32 rows x 128 packed-u32 cols (512B/row); granule = (col>>2)^(row&7)
  char* bounce = lds + wave * 16384;
#pragma unroll
  for (int cf = 0; cf < 8; ++cf) {
    int col = cf * 16 + r0;
    float bias = b1[s * 128 + col];
    int gbase = col >> 2, wsl = (col & 3) * 4;
#pragma unroll
    for (int rf = 0; rf < 2; ++rf)
#pragma unroll
      for (int rr = 0; rr < 4; ++rr) {
        int row = rf * 16 + chunk * 4 + rr;
        float v = fmaxf(acc[rf][cf][rr] + bias, 0.f);
        unsigned short h = rne_bf16(v);
        unsigned short l = rne_bf16(v - bf16f(h));
        int g = gbase ^ (row & 7);
        *(unsigned int*)(bounce + row * 512 + g * 16 + wsl) =
            ((unsigned int)h << 16) | l;
      }
  }

  // ---- bounce read -> layer-2 A fragments (reuse ah/al) ----
  // fragment kk needs packed cols kk*32+chunk*8 .. +7 = granules
  // (kk*8+chunk*2, +1) pre-swizzle; XOR mask is 3 bits so the pair stays adjacent
#pragma unroll
  for (int kk = 0; kk < 4; ++kk)
#pragma unroll
    for (int rf = 0; rf < 2; ++rf) {
      int row = rf * 16 + r0;
      int m = row & 7;
      u32x4 pa = *(const u32x4*)(bounce + row * 512 + (((kk * 8 + chunk * 2)) ^ m) * 16);
      u32x4 pb = *(const u32x4*)(bounce + row * 512 + (((kk * 8 + chunk * 2 + 1)) ^ m) * 16);
      unsigned int h01 = (pa[0] >> 16) | (pa[1] & 0xffff0000u);
      unsigned int h23 = (pa[2] >> 16) | (pa[3] & 0xffff0000u);
      unsigned int h45 = (pb[0] >> 16) | (pb[1] & 0xffff0000u);
      unsigned int h67 = (pb[2] >> 16) | (pb[3] & 0xffff0000u);
      unsigned int l01 = (pa[0] & 0xffffu) | (pa[1] << 16);
      unsigned int l23 = (pa[2] & 0xffffu) | (pa[3] << 16);
      unsigned int l45 = (pb[0] & 0xffffu) | (pb[1] << 16);
      unsigned int l67 = (pb[2] & 0xffffu) | (pb[3] << 16);
      u32x4 hq = {h01, h23, h45, h67};
      u32x4 lq = {l01, l23, l45, l67};
      ah[rf * 4 + kk] = __builtin_bit_cast(short8, hq);
      al[rf * 4 + kk] = __builtin_bit_cast(short8, lq);
    }

  __syncthreads();  // bounce reads done -> Wbuf free for W2

  // ---- stage W2 into LDS ----
#pragma unroll
  for (int it = 0; it < 16; ++it) {
    int c = it * 256 + tid;
    int plane = c >> 11;
    int g = c & 2047;
    int row = g >> 4, gg = g & 15;
    const unsigned short* src = (plane ? gl2 : gh2) + row * 128 + gg * 8;
    short8 v = *(const short8*)src;
    *(short8*)(lds + plane * 32768 + row * 256 + ((gg * 16) ^ ((row & 7) << 4))) = v;
  }
  __syncthreads();  // W2 staged

  // ---- layer 2: acc = h1 * W2 ----
#pragma unroll
  for (int i = 0; i < 2; ++i)
#pragma unroll
    for (int j = 0; j < 8; ++j) acc[i][j] = zero4;

#pragma unroll
  for (int cf = 0; cf < 8; ++cf) {
    int row = cf * 16 + r0;
    int rbase = row * 256;
    int xr = (row & 7) << 4;
    short8 bh[4], bl[4];
#pragma unroll
    for (int k = 0; k < 4; ++k) {
      int off = rbase + (((k * 4 + chunk) * 16) ^ xr);
      bh[k] = *(const short8*)(lds + off);
      bl[k] = *(const short8*)(lds + 32768 + off);
    }
#pragma unroll
    for (int k = 0; k < 4; ++k)
#pragma unroll
      for (int rf = 0; rf < 2; ++rf) {
        int f = rf * 4 + k;
        acc[rf][cf] = __builtin_amdgcn_mfma_f32_16x16x32_bf16(ah[f], bh[k], acc[rf][cf], 0, 0, 0);
        acc[rf][cf] = __builtin_amdgcn_mfma_f32_16x16x32_bf16(ah[f], bl[k], acc[rf][cf], 0, 0, 0);
        acc[rf][cf] = __builtin_amdgcn_mfma_f32_16x16x32_bf16(al[f], bh[k], acc[rf][cf], 0, 0, 0);
      }
  }

  // ---- epilogue 2: e = relu(acc+b2).W3, affine, scatter ----
  float p[2][4] = {{0.f, 0.f, 0.f, 0.f}, {0.f, 0.f, 0.f, 0.f}};
#pragma unroll
  for (int cf = 0; cf < 8; ++cf) {
    int col = cf * 16 + r0;
    float b2v = b2[s * 128 + col];
    float w3v = W3[s * 128 + col];
#pragma unroll
    for (int rf = 0; rf < 2; ++rf)
#pragma unroll
      for (int rr = 0; rr < 4; ++rr)
        p[rf][rr] += fmaxf(acc[rf][cf][rr] + b2v, 0.f) * w3v;
  }
#pragma unroll
  for (int m = 1; m < 16; m <<= 1)
#pragma unroll
    for (int rf = 0; rf < 2; ++rf)
#pragma unroll
      for (int rr = 0; rr < 4; ++rr) p[rf][rr] += __shfl_xor(p[rf][rr], m);

  if (r0 == 0) {
    float sl = slope[s], ic = intercept[s], bb = b3[s];
#pragma unroll
    for (int rf = 0; rf < 2; ++rf)
#pragma unroll
      for (int rr = 0; rr < 4; ++rr) {
        int row = wave * 32 + rf * 16 + chunk * 4 + rr;
        int a = perm[start + row];
        if (a >= 0) e_atom[a] = sl * (p[rf][rr] + bb) + ic;
      }
  }
}

// ---------- kernel 6: deterministic per-image segment sum ----------
__global__ void segsum_kernel(const float* __restrict__ e_atom, const int* __restrict__ img,
                              float* __restrict__ out, int n) {
  int b = blockIdx.x;
  int lo = 0, hi = n;
  while (lo < hi) { int m = (lo + hi) >> 1; if (img[m] < b) lo = m + 1; else hi = m; }
  int lo2 = lo, hi2 = n;
  while (lo2 < hi2) { int m = (lo2 + hi2) >> 1; if (img[m] < b + 1) lo2 = m + 1; else hi2 = m; }
  float sum = 0.f;
  for (int i = lo + threadIdx.x; i < lo2; i += blockDim.x) sum += e_atom[i];
  for (int m = 32; m; m >>= 1) sum += __shfl_down(sum, m);
  __shared__ float part[4];
  int lane = threadIdx.x & 63, wave = threadIdx.x >> 6;
  if (lane == 0) part[wave] = sum;
  __syncthreads();
  if (threadIdx.x == 0) out[b] = part[0] + part[1] + part[2] + part[3];
}

extern "C" void kernel_launch(void* const* d_in, const int* in_sizes, int n_in,
                              void* d_out, int out_size, void* d_ws, size_t ws_size,
                              hipStream_t stream) {
  const float* x         = (const float*)d_in[0];
  const float* W1        = (const float*)d_in[1];
  const float* b1        = (const float*)d_in[2];
  const float* W2        = (const float*)d_in[3];
  const float* b2        = (const float*)d_in[4];
  const float* W3        = (const float*)d_in[5];
  const float* b3        = (const float*)d_in[6];
  const float* slope     = (const float*)d_in[7];
  const float* intercept = (const float*)d_in[8];
  const int* sym         = (const int*)d_in[9];
  const int* img         = (const int*)d_in[10];

  char* ws = (char*)d_ws;
  int* counts   = (int*)ws;                       // 16 B
  int* cursors  = (int*)(ws + 16);                // 16 B
  int* offs     = (int*)(ws + 32);                // 20 B
  int* perm     = (int*)(ws + 64);                // (N+512)*4
  float* e_atom = (float*)(ws + 64 + 1050624);    // N*4
  unsigned short* wt = (unsigned short*)(ws + 64 + 1050624 + 1048576);  // 512 KB

  hipMemsetAsync(counts, 0, 16, stream);
  hipMemsetAsync(perm, 0xFF, (N_ATOMS + 512) * sizeof(int), stream);

  hist_kernel<<<256, 256, 0, stream>>>(sym, counts, N_ATOMS);
  offsets_kernel<<<1, 64, 0, stream>>>(counts, offs, cursors);
  scatter_kernel<<<N_ATOMS / 256, 256, 0, stream>>>(sym, cursors, perm, N_ATOMS);
  wconv_kernel<<<512, 256, 0, stream>>>(W1, W2, wt);
  mlp_gemm<<<N_ATOMS / 128 + NSYM, 256, 65536, stream>>>(x, wt, perm, offs, b1, b2,
                                                         W3, b3, slope, intercept, e_atom);
  segsum_kernel<<<NIMG, 256, 0, stream>>>(e_atom, img, (float*)d_out, N_ATOMS);
}

// Round 8
// 89.748 us; speedup vs baseline: 3.8599x; 1.8523x over previous
//
#include <hip/hip_runtime.h>
#include <hip/hip_bf16.h>
#include <stdint.h>

typedef _Float16 f16x8 __attribute__((ext_vector_type(8)));
typedef __fp16 hf2 __attribute__((ext_vector_type(2)));
typedef float f32x4 __attribute__((ext_vector_type(4)));
typedef unsigned int u32x4 __attribute__((ext_vector_type(4)));

#define N_ATOMS 262144
#define NSYM 4
#define NIMG 1024

// ---------- kernel 1: per-block symbol counts (1024 blocks x 256 atoms) ----------
__global__ void hist_kernel(const int* __restrict__ sym, int* __restrict__ wbh) {
  int b = blockIdx.x;
  int i = b * 256 + threadIdx.x;
  int lane = threadIdx.x & 63, wave = threadIdx.x >> 6;
  __shared__ int wcnt[4][NSYM];
  int s = sym[i];
#pragma unroll
  for (int t = 0; t < NSYM; ++t) {
    unsigned long long m = __ballot(s == t);
    if (lane == 0) wcnt[wave][t] = __popcll(m);
  }
  __syncthreads();
  if (threadIdx.x < NSYM)
    wbh[b * 4 + threadIdx.x] = wcnt[0][threadIdx.x] + wcnt[1][threadIdx.x] +
                               wcnt[2][threadIdx.x] + wcnt[3][threadIdx.x];
}

// ---------- kernel 2: scan -> offsets (128-padded), per-block bases, pad fill ----------
__global__ void offsets_kernel(const int* __restrict__ wbh, int* __restrict__ bases,
                               int* __restrict__ offs, int* __restrict__ perm) {
  __shared__ int wtot[4][NSYM];
  __shared__ int offsh[NSYM + 1];
  __shared__ int totsh[NSYM];
  int t = threadIdx.x, lane = t & 63, wave = t >> 6;
  int pre[4][NSYM];
  int sum[NSYM] = {0, 0, 0, 0};
#pragma unroll
  for (int k = 0; k < 4; ++k)
#pragma unroll
    for (int s2 = 0; s2 < NSYM; ++s2) {
      pre[k][s2] = sum[s2];
      sum[s2] += wbh[(t * 4 + k) * 4 + s2];
    }
  int inc[NSYM] = {sum[0], sum[1], sum[2], sum[3]};
  for (int d = 1; d < 64; d <<= 1) {
#pragma unroll
    for (int s2 = 0; s2 < NSYM; ++s2) {
      int v = __shfl_up(inc[s2], d);
      if (lane >= d) inc[s2] += v;
    }
  }
  if (lane == 63)
#pragma unroll
    for (int s2 = 0; s2 < NSYM; ++s2) wtot[wave][s2] = inc[s2];
  __syncthreads();
  int wb[NSYM];
#pragma unroll
  for (int s2 = 0; s2 < NSYM; ++s2) {
    wb[s2] = 0;
    for (int w = 0; w < wave; ++w) wb[s2] += wtot[w][s2];
  }
  if (t == 255)
#pragma unroll
    for (int s2 = 0; s2 < NSYM; ++s2) totsh[s2] = wb[s2] + inc[s2];
  __syncthreads();
  if (t == 0) {
    int o = 0;
    offsh[0] = 0; offs[0] = 0;
    for (int s2 = 0; s2 < NSYM; ++s2) {
      o += (totsh[s2] + 127) & ~127;
      offsh[s2 + 1] = o; offs[s2 + 1] = o;
    }
  }
  __syncthreads();
#pragma unroll
  for (int k = 0; k < 4; ++k)
#pragma unroll
    for (int s2 = 0; s2 < NSYM; ++s2)
      bases[(t * 4 + k) * 4 + s2] = offsh[s2] + wb[s2] + (inc[s2] - sum[s2]) + pre[k][s2];
  for (int s2 = 0; s2 < NSYM; ++s2) {
    int lo = offsh[s2] + totsh[s2], hi = offsh[s2 + 1];
    for (int i = lo + t; i < hi; i += 256) perm[i] = -1;
  }
}

// ---------- kernel 3: deterministic scatter (base from scan, no atomics) ----------
__global__ void scatter_kernel(const int* __restrict__ sym, const int* __restrict__ bases,
                               int* __restrict__ perm) {
  int b = blockIdx.x;
  int i = b * 256 + threadIdx.x;
  int lane = threadIdx.x & 63, wave = threadIdx.x >> 6;
  __shared__ int wcnt[4][NSYM];
  int s = sym[i];
  unsigned long long mymask = 0;
#pragma unroll
  for (int t = 0; t < NSYM; ++t) {
    unsigned long long m = __ballot(s == t);
    if (lane == 0) wcnt[wave][t] = __popcll(m);
    if (s == t) mymask = m;
  }
  __syncthreads();
  int off = bases[b * 4 + s];
  for (int w = 0; w < wave; ++w) off += wcnt[w][s];
  off += __popcll(mymask & ((1ull << lane) - 1ull));
  perm[off] = i;
}

// ---------- kernel 4: weights -> fp16 planes, PRE-SWIZZLED for global_load_lds ----------
// plane t = layer*4 + s (16384 ushorts, [row h][granule g_s][elem j]):
//   wt[t][h*128 + g_s*8 + j] = f16( W[s][ (g_s^(h&7))*8 + j ][h] )
// so a linear LDS copy yields the XOR-swizzled layout the GEMM B-reads expect.
__global__ void wconv_kernel(const float* __restrict__ W1, const float* __restrict__ W2,
                             unsigned short* __restrict__ wt) {
  int idx = blockIdx.x * 256 + threadIdx.x;  // 0..131071
  int t = idx >> 14;
  int layer = t >> 2, s = t & 3;
  int rem = idx & 16383;
  int h = rem >> 7, u = rem & 127;
  int gs = u >> 3, j = u & 7;
  int d = ((gs ^ (h & 7)) << 3) + j;
  const float* W = layer ? W2 : W1;
  _Float16 hv = (_Float16)W[(s * 128 + d) * 128 + h];  // RNE
  wt[t * 16384 + h * 128 + u] = __builtin_bit_cast(unsigned short, hv);
}

// ---------- kernel 5: fused 2-layer MLP, fp16 2-product ----------
// Block = 4 waves x 32 atoms. LDS 32 KB = one layer's Wh (async-staged via
// global_load_lds from pre-swizzled wt). h1 bounce aliased into the W region
// in two wave-private 8KB half-passes. Products: xh*Wh + xl*Wh (Wl dropped).
__global__ __launch_bounds__(256, 2) void mlp_gemm(
    const float* __restrict__ x, const unsigned short* __restrict__ wt,
    const int* __restrict__ perm, const int* __restrict__ offs,
    const float* __restrict__ b1, const float* __restrict__ b2,
    const float* __restrict__ W3, const float* __restrict__ b3,
    const float* __restrict__ slope, const float* __restrict__ intercept,
    float* __restrict__ e_atom) {
  extern __shared__ char lds[];  // 32 KB

  int start = blockIdx.x * 128;
  if (start >= offs[4]) return;
  int s = 0;
  while (s < 3 && start >= offs[s + 1]) ++s;

  int tid = threadIdx.x;
  int wave = tid >> 6, lane = tid & 63;
  int r0 = lane & 15, chunk = lane >> 4;

  const unsigned short* w1p = wt + (size_t)(0 + s) * 16384;
  const unsigned short* w2p = wt + (size_t)(4 + s) * 16384;

  // ---- issue W1 staging: async DMA, linear dest (source pre-swizzled) ----
#pragma unroll
  for (int it = 0; it < 8; ++it) {
    int gid = it * 256 + wave * 64;  // wave-uniform granule base
    __builtin_amdgcn_global_load_lds((const unsigned int*)(w1p + (size_t)(gid + lane) * 8),
                                     (unsigned int*)(lds + gid * 16), 16, 0, 0);
  }

  // ---- layer-1 A fragments from global x, fp16 hi/lo split in-register ----
  int a0 = perm[start + wave * 32 + r0];
  int a1 = perm[start + wave * 32 + 16 + r0];
  f16x8 ah[8], al[8];  // f = rf*4 + k
#pragma unroll
  for (int rf = 0; rf < 2; ++rf) {
    int atom = rf ? a1 : a0;
    const float* xr = x + (long)(atom < 0 ? 0 : atom) * 128;
#pragma unroll
    for (int k = 0; k < 4; ++k) {
      float4 v0 = make_float4(0.f, 0.f, 0.f, 0.f), v1 = v0;
      if (atom >= 0) {
        v0 = *(const float4*)(xr + k * 32 + chunk * 8);
        v1 = *(const float4*)(xr + k * 32 + chunk * 8 + 4);
      }
      float vv[8] = {v0.x, v0.y, v0.z, v0.w, v1.x, v1.y, v1.z, v1.w};
      unsigned int hw[4], lw[4];
#pragma unroll
      for (int jj = 0; jj < 4; ++jj) {
        hf2 hp = __builtin_amdgcn_cvt_pkrtz(vv[2 * jj], vv[2 * jj + 1]);
        hf2 lp = __builtin_amdgcn_cvt_pkrtz(vv[2 * jj] - (float)hp[0],
                                            vv[2 * jj + 1] - (float)hp[1]);
        hw[jj] = __builtin_bit_cast(unsigned int, hp);
        lw[jj] = __builtin_bit_cast(unsigned int, lp);
      }
      u32x4 hq = {hw[0], hw[1], hw[2], hw[3]};
      u32x4 lq = {lw[0], lw[1], lw[2], lw[3]};
      ah[rf * 4 + k] = __builtin_bit_cast(f16x8, hq);
      al[rf * 4 + k] = __builtin_bit_cast(f16x8, lq);
    }
  }

  __syncthreads();  // W1 staged (barrier drains vmcnt incl. global_load_lds)

  f32x4 zero4 = {0.f, 0.f, 0.f, 0.f};
  f32x4 acc[2][8];
#pragma unroll
  for (int i = 0; i < 2; ++i)
#pragma unroll
    for (int j = 0; j < 8; ++j) acc[i][j] = zero4;

  // ---- layer 1: acc = (xh + xl) * W1h ----
#pragma unroll
  for (int cf = 0; cf < 8; ++cf) {
    int row = cf * 16 + r0;
    int rbase = row * 256, xr2 = (row & 7) << 4;
    f16x8 bh[4];
#pragma unroll
    for (int k = 0; k < 4; ++k)
      bh[k] = *(const f16x8*)(lds + rbase + ((((k * 4 + chunk)) << 4) ^ xr2));
#pragma unroll
    for (int k = 0; k < 4; ++k)
#pragma unroll
      for (int rf = 0; rf < 2; ++rf) {
        acc[rf][cf] = __builtin_amdgcn_mfma_f32_16x16x32_f16(ah[rf * 4 + k], bh[k], acc[rf][cf], 0, 0, 0);
        acc[rf][cf] = __builtin_amdgcn_mfma_f32_16x16x32_f16(al[rf * 4 + k], bh[k], acc[rf][cf], 0, 0, 0);
      }
  }

  __syncthreads();  // all waves done reading W1h -> region reusable as bounce

  // ---- bounce: h1 = relu(acc+b1) -> fp16 (hi<<16)|lo, wave-private 8KB,
  //      two half-passes (cols 0-63 then 64-127); swizzle:
  //      col'' = col' ^ (((row>>2)&3)<<4) ^ ((row&3)<<2)
  char* bounce = lds + wave * 8192;
#pragma unroll
  for (int hp2 = 0; hp2 < 2; ++hp2) {
#pragma unroll
    for (int cf4 = 0; cf4 < 4; ++cf4) {
      int cf = hp2 * 4 + cf4;
      int col = cf * 16 + r0;
      float bias = b1[s * 128 + col];
      int colp = cf4 * 16 + r0;
#pragma unroll
      for (int rf = 0; rf < 2; ++rf)
#pragma unroll
        for (int rr = 0; rr < 4; ++rr) {
          int row = rf * 16 + chunk * 4 + rr;  // (row>>2)&3 = chunk, row&3 = rr
          float v = fmaxf(acc[rf][cf][rr] + bias, 0.f);
          hf2 hv = __builtin_amdgcn_cvt_pkrtz(v, 0.f);
          hf2 pk = __builtin_amdgcn_cvt_pkrtz(v - (float)hv[0], (float)hv[0]);
          int cc = colp ^ (chunk << 4) ^ (rr << 2);
          *(unsigned int*)(bounce + row * 256 + cc * 4) = __builtin_bit_cast(unsigned int, pk);
        }
    }
    // read frags kk = hp2*2, hp2*2+1 (overwrite ah/al with h1 hi/lo)
#pragma unroll
    for (int kk2 = 0; kk2 < 2; ++kk2) {
      int kk = hp2 * 2 + kk2;
#pragma unroll
      for (int rf = 0; rf < 2; ++rf) {
        int row = rf * 16 + r0;  // (row>>2)&3 = r0>>2, row&3 = r0&3
        int xr3 = ((r0 >> 2) << 4) ^ ((r0 & 3) << 2);
        int c0 = kk2 * 32 + chunk * 8;
        u32x4 pa = *(const u32x4*)(bounce + row * 256 + (c0 ^ xr3) * 4);
        u32x4 pb = *(const u32x4*)(bounce + row * 256 + ((c0 + 4) ^ xr3) * 4);
        unsigned int h01 = (pa[0] >> 16) | (pa[1] & 0xffff0000u);
        unsigned int h23 = (pa[2] >> 16) | (pa[3] & 0xffff0000u);
        unsigned int h45 = (pb[0] >> 16) | (pb[1] & 0xffff0000u);
        unsigned int h67 = (pb[2] >> 16) | (pb[3] & 0xffff0000u);
        unsigned int l01 = (pa[0] & 0xffffu) | (pa[1] << 16);
        unsigned int l23 = (pa[2] & 0xffffu) | (pa[3] << 16);
        unsigned int l45 = (pb[0] & 0xffffu) | (pb[1] << 16);
        unsigned int l67 = (pb[2] & 0xffffu) | (pb[3] << 16);
        u32x4 hq = {h01, h23, h45, h67};
        u32x4 lq = {l01, l23, l45, l67};
        ah[rf * 4 + kk] = __builtin_bit_cast(f16x8, hq);
        al[rf * 4 + kk] = __builtin_bit_cast(f16x8, lq);
      }
    }
  }

  __syncthreads();  // bounce reads done -> region free for W2h

  // ---- stage W2h (async DMA) ----
#pragma unroll
  for (int it = 0; it < 8; ++it) {
    int gid = it * 256 + wave * 64;
    __builtin_amdgcn_global_load_lds((const unsigned int*)(w2p + (size_t)(gid + lane) * 8),
                                     (unsigned int*)(lds + gid * 16), 16, 0, 0);
  }
  __syncthreads();  // W2h staged

  // ---- layer 2: acc = (h1h + h1l) * W2h ----
#pragma unroll
  for (int i = 0; i < 2; ++i)
#pragma unroll
    for (int j = 0; j < 8; ++j) acc[i][j] = zero4;

#pragma unroll
  for (int cf = 0; cf < 8; ++cf) {
    int row = cf * 16 + r0;
    int rbase = row * 256, xr2 = (row & 7) << 4;
    f16x8 bh[4];
#pragma unroll
    for (int k = 0; k < 4; ++k)
      bh[k] = *(const f16x8*)(lds + rbase + ((((k * 4 + chunk)) << 4) ^ xr2));
#pragma unroll
    for (int k = 0; k < 4; ++k)
#pragma unroll
      for (int rf = 0; rf < 2; ++rf) {
        acc[rf][cf] = __builtin_amdgcn_mfma_f32_16x16x32_f16(ah[rf * 4 + k], bh[k], acc[rf][cf], 0, 0, 0);
        acc[rf][cf] = __builtin_amdgcn_mfma_f32_16x16x32_f16(al[rf * 4 + k], bh[k], acc[rf][cf], 0, 0, 0);
      }
  }

  // ---- epilogue: e = relu(acc+b2).W3, affine, scatter ----
  float p[2][4] = {{0.f, 0.f, 0.f, 0.f}, {0.f, 0.f, 0.f, 0.f}};
#pragma unroll
  for (int cf = 0; cf < 8; ++cf) {
    int col = cf * 16 + r0;
    float b2v = b2[s * 128 + col];
    float w3v = W3[s * 128 + col];
#pragma unroll
    for (int rf = 0; rf < 2; ++rf)
#pragma unroll
      for (int rr = 0; rr < 4; ++rr)
        p[rf][rr] += fmaxf(acc[rf][cf][rr] + b2v, 0.f) * w3v;
  }
#pragma unroll
  for (int m = 1; m < 16; m <<= 1)
#pragma unroll
    for (int rf = 0; rf < 2; ++rf)
#pragma unroll
      for (int rr = 0; rr < 4; ++rr) p[rf][rr] += __shfl_xor(p[rf][rr], m);

  if (r0 == 0) {
    float sl = slope[s], ic = intercept[s], bb = b3[s];
#pragma unroll
    for (int rf = 0; rf < 2; ++rf)
#pragma unroll
      for (int rr = 0; rr < 4; ++rr) {
        int row = wave * 32 + rf * 16 + chunk * 4 + rr;
        int a = perm[start + row];
        if (a >= 0) e_atom[a] = sl * (p[rf][rr] + bb) + ic;
      }
  }
}

// ---------- kernel 6: deterministic per-image segment sum ----------
__global__ void segsum_kernel(const float* __restrict__ e_atom, const int* __restrict__ img,
                              float* __restrict__ out, int n) {
  int b = blockIdx.x;
  int lo = 0, hi = n;
  while (lo < hi) { int m = (lo + hi) >> 1; if (img[m] < b) lo = m + 1; else hi = m; }
  int lo2 = lo, hi2 = n;
  while (lo2 < hi2) { int m = (lo2 + hi2) >> 1; if (img[m] < b + 1) lo2 = m + 1; else hi2 = m; }
  float sum = 0.f;
  for (int i = lo + threadIdx.x; i < lo2; i += blockDim.x) sum += e_atom[i];
  for (int m = 32; m; m >>= 1) sum += __shfl_down(sum, m);
  __shared__ float part[4];
  int lane = threadIdx.x & 63, wave = threadIdx.x >> 6;
  if (lane == 0) part[wave] = sum;
  __syncthreads();
  if (threadIdx.x == 0) out[b] = part[0] + part[1] + part[2] + part[3];
}

extern "C" void kernel_launch(void* const* d_in, const int* in_sizes, int n_in,
                              void* d_out, int out_size, void* d_ws, size_t ws_size,
                              hipStream_t stream) {
  const float* x         = (const float*)d_in[0];
  const float* W1        = (const float*)d_in[1];
  const float* b1        = (const float*)d_in[2];
  const float* W2        = (const float*)d_in[3];
  const float* b2        = (const float*)d_in[4];
  const float* W3        = (const float*)d_in[5];
  const float* b3        = (const float*)d_in[6];
  const float* slope     = (const float*)d_in[7];
  const float* intercept = (const float*)d_in[8];
  const int* sym         = (const int*)d_in[9];
  const int* img         = (const int*)d_in[10];

  char* ws = (char*)d_ws;
  int* wbh    = (int*)ws;                          // 1024*4*4 = 16384 B
  int* bases  = (int*)(ws + 16384);                // 16384 B
  int* offs   = (int*)(ws + 32768);                // 20 B (pad to 64)
  int* perm   = (int*)(ws + 32832);                // (N+512)*4 = 1050624 B
  float* e_atom = (float*)(ws + 32832 + 1050624);  // N*4
  unsigned short* wt = (unsigned short*)(ws + 32832 + 1050624 + 1048576);  // 256 KB

  hist_kernel<<<1024, 256, 0, stream>>>(sym, wbh);
  offsets_kernel<<<1, 256, 0, stream>>>(wbh, bases, offs, perm);
  scatter_kernel<<<1024, 256, 0, stream>>>(sym, bases, perm);
  wconv_kernel<<<512, 256, 0, stream>>>(W1, W2, wt);
  mlp_gemm<<<N_ATOMS / 128 + NSYM, 256, 32768, stream>>>(x, wt, perm, offs, b1, b2,
                                                         W3, b3, slope, intercept, e_atom);
  segsum_kernel<<<NIMG, 256, 0, stream>>>(e_atom, img, (float*)d_out, N_ATOMS);
}

// Round 9
// 80.172 us; speedup vs baseline: 4.3209x; 1.1194x over previous
//
#include <hip/hip_runtime.h>
#include <hip/hip_bf16.h>
#include <stdint.h>

typedef _Float16 f16x8 __attribute__((ext_vector_type(8)));
typedef __fp16 hf2 __attribute__((ext_vector_type(2)));
typedef float f32x4 __attribute__((ext_vector_type(4)));
typedef unsigned int u32x4 __attribute__((ext_vector_type(4)));

#define N_ATOMS 262144
#define NSYM 4
#define NIMG 1024

// ---------- kernel 1: per-block symbol counts (1024 blocks x 256 atoms) ----------
__global__ void hist_kernel(const int* __restrict__ sym, int* __restrict__ wbh) {
  int b = blockIdx.x;
  int i = b * 256 + threadIdx.x;
  int lane = threadIdx.x & 63, wave = threadIdx.x >> 6;
  __shared__ int wcnt[4][NSYM];
  int s = sym[i];
#pragma unroll
  for (int t = 0; t < NSYM; ++t) {
    unsigned long long m = __ballot(s == t);
    if (lane == 0) wcnt[wave][t] = __popcll(m);
  }
  __syncthreads();
  if (threadIdx.x < NSYM)
    wbh[b * 4 + threadIdx.x] = wcnt[0][threadIdx.x] + wcnt[1][threadIdx.x] +
                               wcnt[2][threadIdx.x] + wcnt[3][threadIdx.x];
}

// ---------- kernel 2: scan -> offsets (256-padded), per-block bases, pad fill ----------
__global__ void offsets_kernel(const int* __restrict__ wbh, int* __restrict__ bases,
                               int* __restrict__ offs, int* __restrict__ perm) {
  __shared__ int wtot[4][NSYM];
  __shared__ int offsh[NSYM + 1];
  __shared__ int totsh[NSYM];
  int t = threadIdx.x, lane = t & 63, wave = t >> 6;
  int pre[4][NSYM];
  int sum[NSYM] = {0, 0, 0, 0};
#pragma unroll
  for (int k = 0; k < 4; ++k)
#pragma unroll
    for (int s2 = 0; s2 < NSYM; ++s2) {
      pre[k][s2] = sum[s2];
      sum[s2] += wbh[(t * 4 + k) * 4 + s2];
    }
  int inc[NSYM] = {sum[0], sum[1], sum[2], sum[3]};
  for (int d = 1; d < 64; d <<= 1) {
#pragma unroll
    for (int s2 = 0; s2 < NSYM; ++s2) {
      int v = __shfl_up(inc[s2], d);
      if (lane >= d) inc[s2] += v;
    }
  }
  if (lane == 63)
#pragma unroll
    for (int s2 = 0; s2 < NSYM; ++s2) wtot[wave][s2] = inc[s2];
  __syncthreads();
  int wb[NSYM];
#pragma unroll
  for (int s2 = 0; s2 < NSYM; ++s2) {
    wb[s2] = 0;
    for (int w = 0; w < wave; ++w) wb[s2] += wtot[w][s2];
  }
  if (t == 255)
#pragma unroll
    for (int s2 = 0; s2 < NSYM; ++s2) totsh[s2] = wb[s2] + inc[s2];
  __syncthreads();
  if (t == 0) {
    int o = 0;
    offsh[0] = 0; offs[0] = 0;
    for (int s2 = 0; s2 < NSYM; ++s2) {
      o += (totsh[s2] + 255) & ~255;
      offsh[s2 + 1] = o; offs[s2 + 1] = o;
    }
  }
  __syncthreads();
#pragma unroll
  for (int k = 0; k < 4; ++k)
#pragma unroll
    for (int s2 = 0; s2 < NSYM; ++s2)
      bases[(t * 4 + k) * 4 + s2] = offsh[s2] + wb[s2] + (inc[s2] - sum[s2]) + pre[k][s2];
  for (int s2 = 0; s2 < NSYM; ++s2) {
    int lo = offsh[s2] + totsh[s2], hi = offsh[s2 + 1];
    for (int i = lo + t; i < hi; i += 256) perm[i] = -1;
  }
}

// ---------- kernel 3: deterministic scatter (base from scan, no atomics) ----------
__global__ void scatter_kernel(const int* __restrict__ sym, const int* __restrict__ bases,
                               int* __restrict__ perm) {
  int b = blockIdx.x;
  int i = b * 256 + threadIdx.x;
  int lane = threadIdx.x & 63, wave = threadIdx.x >> 6;
  __shared__ int wcnt[4][NSYM];
  int s = sym[i];
  unsigned long long mymask = 0;
#pragma unroll
  for (int t = 0; t < NSYM; ++t) {
    unsigned long long m = __ballot(s == t);
    if (lane == 0) wcnt[wave][t] = __popcll(m);
    if (s == t) mymask = m;
  }
  __syncthreads();
  int off = bases[b * 4 + s];
  for (int w = 0; w < wave; ++w) off += wcnt[w][s];
  off += __popcll(mymask & ((1ull << lane) - 1ull));
  perm[off] = i;
}

// ---------- kernel 4: weights -> fp16 planes, PRE-SWIZZLED for global_load_lds ----------
// plane t = layer*4 + s (16384 ushorts = 32KB, [row h][granule g_s][elem j]):
//   wt[t][h*128 + g_s*8 + j] = f16( W[s][ (g_s^(h&7))*8 + j ][h] )
__global__ void wconv_kernel(const float* __restrict__ W1, const float* __restrict__ W2,
                             unsigned short* __restrict__ wt) {
  int idx = blockIdx.x * 256 + threadIdx.x;  // 0..131071
  int t = idx >> 14;
  int layer = t >> 2, s = t & 3;
  int rem = idx & 16383;
  int h = rem >> 7, u = rem & 127;
  int gs = u >> 3, j = u & 7;
  int d = ((gs ^ (h & 7)) << 3) + j;
  const float* W = layer ? W2 : W1;
  _Float16 hv = (_Float16)W[(s * 128 + d) * 128 + h];  // RNE
  wt[t * 16384 + h * 128 + u] = __builtin_bit_cast(unsigned short, hv);
}

// ---------- kernel 5: fused 2-layer MLP, persistent multi-tile ----------
// 256 blocks (1/CU) x 8 waves x 32 atoms = 256-atom tiles. Symbol fixed per block
// (blockIdx>>6); tiles strided by 64. LDS 128KB: W1h[0,32K)+W2h[32K,64K) staged
// ONCE, bounce per-wave 8KB at [64K..128K). No barriers in the tile loop.
// Next tile's perm+x loads issued during current tile's compute (T14).
__global__ __launch_bounds__(512, 2) void mlp_gemm(
    const float* __restrict__ x, const unsigned short* __restrict__ wt,
    const int* __restrict__ perm, const int* __restrict__ offs,
    const float* __restrict__ b1, const float* __restrict__ b2,
    const float* __restrict__ W3, const float* __restrict__ b3,
    const float* __restrict__ slope, const float* __restrict__ intercept,
    float* __restrict__ e_atom) {
  extern __shared__ char lds[];  // 128 KB

  int s = blockIdx.x >> 6;
  int kblk = blockIdx.x & 63;
  int base = offs[s];
  int T = (offs[s + 1] - base) >> 8;  // 256-atom tiles in this symbol

  int tid = threadIdx.x;
  int wave = tid >> 6, lane = tid & 63;
  int r0 = lane & 15, chunk = lane >> 4;
  char* bounce = lds + 65536 + wave * 8192;

  const unsigned short* w1p = wt + (size_t)(0 + s) * 16384;
  const unsigned short* w2p = wt + (size_t)(4 + s) * 16384;

  // ---- stage W1h+W2h once: 4096 granules of 16B, async DMA, linear dest ----
#pragma unroll
  for (int it = 0; it < 8; ++it) {
    int gb = it * 512 + wave * 64;  // wave-uniform granule base
    const unsigned short* src = (gb >= 2048) ? (w2p + (size_t)(gb - 2048 + lane) * 8)
                                             : (w1p + (size_t)(gb + lane) * 8);
    __builtin_amdgcn_global_load_lds((const unsigned int*)src,
                                     (unsigned int*)(lds + (size_t)gb * 16), 16, 0, 0);
  }

  // ---- hoist per-symbol constants ----
  float b1v[8], b2v[8], w3v[8];
#pragma unroll
  for (int cf = 0; cf < 8; ++cf) {
    b1v[cf] = b1[s * 128 + cf * 16 + r0];
    b2v[cf] = b2[s * 128 + cf * 16 + r0];
    w3v[cf] = W3[s * 128 + cf * 16 + r0];
  }
  float sl = slope[s], ic = intercept[s], bb = b3[s];

  // ---- x prefetch helper: 16 float4 per lane (32 atoms x 32B each) ----
  float4 raw[16];
  auto prefetch_x = [&](int atom0, int atom1) {
#pragma unroll
    for (int rf = 0; rf < 2; ++rf) {
      int atom = rf ? atom1 : atom0;
      const float* xr = x + (long)(atom < 0 ? 0 : atom) * 128;
#pragma unroll
      for (int kk = 0; kk < 4; ++kk) {
        float4 v0 = make_float4(0.f, 0.f, 0.f, 0.f), v1 = v0;
        if (atom >= 0) {
          v0 = *(const float4*)(xr + kk * 32 + chunk * 8);
          v1 = *(const float4*)(xr + kk * 32 + chunk * 8 + 4);
        }
        raw[rf * 8 + kk * 2] = v0;
        raw[rf * 8 + kk * 2 + 1] = v1;
      }
    }
  };

  // ---- prologue: tile kblk's perm + x loads (overlap with W DMA) ----
  int t = kblk;
  int a0 = -1, a1 = -1;
  if (t < T) {
    a0 = perm[base + (t << 8) + wave * 32 + r0];
    a1 = perm[base + (t << 8) + wave * 32 + 16 + r0];
  }
  prefetch_x(a0, a1);

  __syncthreads();  // W staged (drains all vmcnt incl. prologue x)

  f32x4 zero4 = {0.f, 0.f, 0.f, 0.f};
  f16x8 ah[8], al[8];

  for (; t < T; t += 64) {
    int tn = t + 64;
    // issue next tile's perm loads early
    int na0 = -1, na1 = -1;
    if (tn < T) {
      na0 = perm[base + (tn << 8) + wave * 32 + r0];
      na1 = perm[base + (tn << 8) + wave * 32 + 16 + r0];
    }

    // ---- convert raw -> fp16 hi/lo fragments ----
#pragma unroll
    for (int rf = 0; rf < 2; ++rf)
#pragma unroll
      for (int kk = 0; kk < 4; ++kk) {
        float4 v0 = raw[rf * 8 + kk * 2], v1 = raw[rf * 8 + kk * 2 + 1];
        float vv[8] = {v0.x, v0.y, v0.z, v0.w, v1.x, v1.y, v1.z, v1.w};
        unsigned int hw[4], lw[4];
#pragma unroll
        for (int jj = 0; jj < 4; ++jj) {
          hf2 hp = __builtin_amdgcn_cvt_pkrtz(vv[2 * jj], vv[2 * jj + 1]);
          hf2 lp = __builtin_amdgcn_cvt_pkrtz(vv[2 * jj] - (float)hp[0],
                                              vv[2 * jj + 1] - (float)hp[1]);
          hw[jj] = __builtin_bit_cast(unsigned int, hp);
          lw[jj] = __builtin_bit_cast(unsigned int, lp);
        }
        u32x4 hq = {hw[0], hw[1], hw[2], hw[3]};
        u32x4 lq = {lw[0], lw[1], lw[2], lw[3]};
        ah[rf * 4 + kk] = __builtin_bit_cast(f16x8, hq);
        al[rf * 4 + kk] = __builtin_bit_cast(f16x8, lq);
      }

    // ---- layer 1: acc = (xh + xl) * W1h (B from LDS[0,32K)) ----
    f32x4 acc[2][8];
#pragma unroll
    for (int i = 0; i < 2; ++i)
#pragma unroll
      for (int j = 0; j < 8; ++j) acc[i][j] = zero4;

#pragma unroll
    for (int cf = 0; cf < 8; ++cf) {
      int row = cf * 16 + r0;
      int rbase = row * 256, xr2 = (row & 7) << 4;
      f16x8 bh[4];
#pragma unroll
      for (int k = 0; k < 4; ++k)
        bh[k] = *(const f16x8*)(lds + rbase + ((((k * 4 + chunk)) << 4) ^ xr2));
#pragma unroll
      for (int k = 0; k < 4; ++k)
#pragma unroll
        for (int rf = 0; rf < 2; ++rf) {
          acc[rf][cf] = __builtin_amdgcn_mfma_f32_16x16x32_f16(ah[rf * 4 + k], bh[k], acc[rf][cf], 0, 0, 0);
          acc[rf][cf] = __builtin_amdgcn_mfma_f32_16x16x32_f16(al[rf * 4 + k], bh[k], acc[rf][cf], 0, 0, 0);
        }
    }

    // ---- issue next tile's x loads (land under bounce + layer 2) ----
    if (tn < T) prefetch_x(na0, na1);

    // ---- bounce: h1 -> fp16 (hi<<16)|lo, wave-private, 2 half-passes ----
#pragma unroll
    for (int hp2 = 0; hp2 < 2; ++hp2) {
#pragma unroll
      for (int cf4 = 0; cf4 < 4; ++cf4) {
        int cf = hp2 * 4 + cf4;
        float bias = b1v[cf];
        int colp = cf4 * 16 + r0;
#pragma unroll
        for (int rf = 0; rf < 2; ++rf)
#pragma unroll
          for (int rr = 0; rr < 4; ++rr) {
            int row = rf * 16 + chunk * 4 + rr;
            float v = fmaxf(acc[rf][cf][rr] + bias, 0.f);
            hf2 hv = __builtin_amdgcn_cvt_pkrtz(v, 0.f);
            hf2 pk = __builtin_amdgcn_cvt_pkrtz(v - (float)hv[0], (float)hv[0]);
            int cc = colp ^ (chunk << 4) ^ (rr << 2);
            *(unsigned int*)(bounce + row * 256 + cc * 4) = __builtin_bit_cast(unsigned int, pk);
          }
      }
#pragma unroll
      for (int kk2 = 0; kk2 < 2; ++kk2) {
        int kk = hp2 * 2 + kk2;
#pragma unroll
        for (int rf = 0; rf < 2; ++rf) {
          int row = rf * 16 + r0;
          int xr3 = ((r0 >> 2) << 4) ^ ((r0 & 3) << 2);
          int c0 = kk2 * 32 + chunk * 8;
          u32x4 pa = *(const u32x4*)(bounce + row * 256 + (c0 ^ xr3) * 4);
          u32x4 pb = *(const u32x4*)(bounce + row * 256 + ((c0 + 4) ^ xr3) * 4);
          unsigned int h01 = (pa[0] >> 16) | (pa[1] & 0xffff0000u);
          unsigned int h23 = (pa[2] >> 16) | (pa[3] & 0xffff0000u);
          unsigned int h45 = (pb[0] >> 16) | (pb[1] & 0xffff0000u);
          unsigned int h67 = (pb[2] >> 16) | (pb[3] & 0xffff0000u);
          unsigned int l01 = (pa[0] & 0xffffu) | (pa[1] << 16);
          unsigned int l23 = (pa[2] & 0xffffu) | (pa[3] << 16);
          unsigned int l45 = (pb[0] & 0xffffu) | (pb[1] << 16);
          unsigned int l67 = (pb[2] & 0xffffu) | (pb[3] << 16);
          u32x4 hq = {h01, h23, h45, h67};
          u32x4 lq = {l01, l23, l45, l67};
          ah[rf * 4 + kk] = __builtin_bit_cast(f16x8, hq);
          al[rf * 4 + kk] = __builtin_bit_cast(f16x8, lq);
        }
      }
    }

    // ---- layer 2: acc = (h1h + h1l) * W2h (B from LDS[32K,64K)) ----
#pragma unroll
    for (int i = 0; i < 2; ++i)
#pragma unroll
      for (int j = 0; j < 8; ++j) acc[i][j] = zero4;

#pragma unroll
    for (int cf = 0; cf < 8; ++cf) {
      int row = cf * 16 + r0;
      int rbase = 32768 + row * 256, xr2 = (row & 7) << 4;
      f16x8 bh[4];
#pragma unroll
      for (int k = 0; k < 4; ++k)
        bh[k] = *(const f16x8*)(lds + rbase + ((((k * 4 + chunk)) << 4) ^ xr2));
#pragma unroll
      for (int k = 0; k < 4; ++k)
#pragma unroll
        for (int rf = 0; rf < 2; ++rf) {
          acc[rf][cf] = __builtin_amdgcn_mfma_f32_16x16x32_f16(ah[rf * 4 + k], bh[k], acc[rf][cf], 0, 0, 0);
          acc[rf][cf] = __builtin_amdgcn_mfma_f32_16x16x32_f16(al[rf * 4 + k], bh[k], acc[rf][cf], 0, 0, 0);
        }
    }

    // ---- epilogue: e = relu(acc+b2).W3, affine, scatter ----
    float p[2][4] = {{0.f, 0.f, 0.f, 0.f}, {0.f, 0.f, 0.f, 0.f}};
#pragma unroll
    for (int cf = 0; cf < 8; ++cf) {
#pragma unroll
      for (int rf = 0; rf < 2; ++rf)
#pragma unroll
        for (int rr = 0; rr < 4; ++rr)
          p[rf][rr] += fmaxf(acc[rf][cf][rr] + b2v[cf], 0.f) * w3v[cf];
    }
#pragma unroll
    for (int m = 1; m < 16; m <<= 1)
#pragma unroll
      for (int rf = 0; rf < 2; ++rf)
#pragma unroll
        for (int rr = 0; rr < 4; ++rr) p[rf][rr] += __shfl_xor(p[rf][rr], m);

    if (r0 == 0) {
#pragma unroll
      for (int rf = 0; rf < 2; ++rf)
#pragma unroll
        for (int rr = 0; rr < 4; ++rr) {
          int row = wave * 32 + rf * 16 + chunk * 4 + rr;
          int a = perm[base + (t << 8) + row];
          if (a >= 0) e_atom[a] = sl * (p[rf][rr] + bb) + ic;
        }
    }

    a0 = na0; a1 = na1;
  }
}

// ---------- kernel 6: deterministic per-image segment sum ----------
__global__ void segsum_kernel(const float* __restrict__ e_atom, const int* __restrict__ img,
                              float* __restrict__ out, int n) {
  int b = blockIdx.x;
  int lo = 0, hi = n;
  while (lo < hi) { int m = (lo + hi) >> 1; if (img[m] < b) lo = m + 1; else hi = m; }
  int lo2 = lo, hi2 = n;
  while (lo2 < hi2) { int m = (lo2 + hi2) >> 1; if (img[m] < b + 1) lo2 = m + 1; else hi2 = m; }
  float sum = 0.f;
  for (int i = lo + threadIdx.x; i < lo2; i += blockDim.x) sum += e_atom[i];
  for (int m = 32; m; m >>= 1) sum += __shfl_down(sum, m);
  __shared__ float part[4];
  int lane = threadIdx.x & 63, wave = threadIdx.x >> 6;
  if (lane == 0) part[wave] = sum;
  __syncthreads();
  if (threadIdx.x == 0) out[b] = part[0] + part[1] + part[2] + part[3];
}

extern "C" void kernel_launch(void* const* d_in, const int* in_sizes, int n_in,
                              void* d_out, int out_size, void* d_ws, size_t ws_size,
                              hipStream_t stream) {
  const float* x         = (const float*)d_in[0];
  const float* W1        = (const float*)d_in[1];
  const float* b1        = (const float*)d_in[2];
  const float* W2        = (const float*)d_in[3];
  const float* b2        = (const float*)d_in[4];
  const float* W3        = (const float*)d_in[5];
  const float* b3        = (const float*)d_in[6];
  const float* slope     = (const float*)d_in[7];
  const float* intercept = (const float*)d_in[8];
  const int* sym         = (const int*)d_in[9];
  const int* img         = (const int*)d_in[10];

  char* ws = (char*)d_ws;
  int* wbh    = (int*)ws;                          // 16384 B
  int* bases  = (int*)(ws + 16384);                // 16384 B
  int* offs   = (int*)(ws + 32768);                // 64 B
  int* perm   = (int*)(ws + 32832);                // (N+1024)*4 = 1052672 B
  float* e_atom = (float*)(ws + 32832 + 1052672);  // N*4
  unsigned short* wt = (unsigned short*)(ws + 32832 + 1052672 + 1048576);  // 256 KB

  hist_kernel<<<1024, 256, 0, stream>>>(sym, wbh);
  offsets_kernel<<<1, 256, 0, stream>>>(wbh, bases, offs, perm);
  scatter_kernel<<<1024, 256, 0, stream>>>(sym, bases, perm);
  wconv_kernel<<<512, 256, 0, stream>>>(W1, W2, wt);
  mlp_gemm<<<256, 512, 131072, stream>>>(x, wt, perm, offs, b1, b2,
                                         W3, b3, slope, intercept, e_atom);
  segsum_kernel<<<NIMG, 256, 0, stream>>>(e_atom, img, (float*)d_out, N_ATOMS);
}

// Round 10
// 76.986 us; speedup vs baseline: 4.4997x; 1.0414x over previous
//
#include <hip/hip_runtime.h>
#include <hip/hip_bf16.h>
#include <stdint.h>

typedef _Float16 f16x8 __attribute__((ext_vector_type(8)));
typedef float f32x4 __attribute__((ext_vector_type(4)));
typedef unsigned int u32x4 __attribute__((ext_vector_type(4)));

#define N_ATOMS 262144
#define NSYM 4
#define NIMG 1024

// ---------- kernel 1: per-block symbol counts ----------
__global__ void hist_kernel(const int* __restrict__ sym, int* __restrict__ wbh) {
  int b = blockIdx.x;
  int i = b * 256 + threadIdx.x;
  int lane = threadIdx.x & 63, wave = threadIdx.x >> 6;
  __shared__ int wcnt[4][NSYM];
  int s = sym[i];
#pragma unroll
  for (int t = 0; t < NSYM; ++t) {
    unsigned long long m = __ballot(s == t);
    if (lane == 0) wcnt[wave][t] = __popcll(m);
  }
  __syncthreads();
  if (threadIdx.x < NSYM)
    wbh[b * 4 + threadIdx.x] = wcnt[0][threadIdx.x] + wcnt[1][threadIdx.x] +
                               wcnt[2][threadIdx.x] + wcnt[3][threadIdx.x];
}

// ---------- kernel 2: scan -> offsets (256-padded), per-block bases, pad fill ----------
__global__ void offsets_kernel(const int* __restrict__ wbh, int* __restrict__ bases,
                               int* __restrict__ offs, int* __restrict__ perm) {
  __shared__ int wtot[4][NSYM];
  __shared__ int offsh[NSYM + 1];
  __shared__ int totsh[NSYM];
  int t = threadIdx.x, lane = t & 63, wave = t >> 6;
  int pre[4][NSYM];
  int sum[NSYM] = {0, 0, 0, 0};
#pragma unroll
  for (int k = 0; k < 4; ++k)
#pragma unroll
    for (int s2 = 0; s2 < NSYM; ++s2) {
      pre[k][s2] = sum[s2];
      sum[s2] += wbh[(t * 4 + k) * 4 + s2];
    }
  int inc[NSYM] = {sum[0], sum[1], sum[2], sum[3]};
  for (int d = 1; d < 64; d <<= 1) {
#pragma unroll
    for (int s2 = 0; s2 < NSYM; ++s2) {
      int v = __shfl_up(inc[s2], d);
      if (lane >= d) inc[s2] += v;
    }
  }
  if (lane == 63)
#pragma unroll
    for (int s2 = 0; s2 < NSYM; ++s2) wtot[wave][s2] = inc[s2];
  __syncthreads();
  int wb[NSYM];
#pragma unroll
  for (int s2 = 0; s2 < NSYM; ++s2) {
    wb[s2] = 0;
    for (int w = 0; w < wave; ++w) wb[s2] += wtot[w][s2];
  }
  if (t == 255)
#pragma unroll
    for (int s2 = 0; s2 < NSYM; ++s2) totsh[s2] = wb[s2] + inc[s2];
  __syncthreads();
  if (t == 0) {
    int o = 0;
    offsh[0] = 0; offs[0] = 0;
    for (int s2 = 0; s2 < NSYM; ++s2) {
      o += (totsh[s2] + 255) & ~255;
      offsh[s2 + 1] = o; offs[s2 + 1] = o;
    }
  }
  __syncthreads();
#pragma unroll
  for (int k = 0; k < 4; ++k)
#pragma unroll
    for (int s2 = 0; s2 < NSYM; ++s2)
      bases[(t * 4 + k) * 4 + s2] = offsh[s2] + wb[s2] + (inc[s2] - sum[s2]) + pre[k][s2];
  for (int s2 = 0; s2 < NSYM; ++s2) {
    int lo = offsh[s2] + totsh[s2], hi = offsh[s2 + 1];
    for (int i = lo + t; i < hi; i += 256) perm[i] = -1;
  }
}

// ---------- kernel 3: deterministic scatter ----------
__global__ void scatter_kernel(const int* __restrict__ sym, const int* __restrict__ bases,
                               int* __restrict__ perm) {
  int b = blockIdx.x;
  int i = b * 256 + threadIdx.x;
  int lane = threadIdx.x & 63, wave = threadIdx.x >> 6;
  __shared__ int wcnt[4][NSYM];
  int s = sym[i];
  unsigned long long mymask = 0;
#pragma unroll
  for (int t = 0; t < NSYM; ++t) {
    unsigned long long m = __ballot(s == t);
    if (lane == 0) wcnt[wave][t] = __popcll(m);
    if (s == t) mymask = m;
  }
  __syncthreads();
  int off = bases[b * 4 + s];
  for (int w = 0; w < wave; ++w) off += wcnt[w][s];
  off += __popcll(mymask & ((1ull << lane) - 1ull));
  perm[off] = i;
}

// ---------- kernel 4: weights -> fp16 planes, PRE-SWIZZLED for global_load_lds ----------
__global__ void wconv_kernel(const float* __restrict__ W1, const float* __restrict__ W2,
                             unsigned short* __restrict__ wt) {
  int idx = blockIdx.x * 256 + threadIdx.x;  // 0..131071
  int t = idx >> 14;
  int layer = t >> 2, s = t & 3;
  int rem = idx & 16383;
  int h = rem >> 7, u = rem & 127;
  int gs = u >> 3, j = u & 7;
  int d = ((gs ^ (h & 7)) << 3) + j;
  const float* W = layer ? W2 : W1;
  _Float16 hv = (_Float16)W[(s * 128 + d) * 128 + h];  // RNE
  wt[t * 16384 + h * 128 + u] = __builtin_bit_cast(unsigned short, hv);
}

// ---------- kernel 5: fused 2-layer MLP, persistent, single-fp16, spill-free ----------
// 256 blocks x 8 waves x 32 atoms/wave = 256-atom tiles; symbol = blockIdx>>6.
// LDS 128KB: W1h[0,32K) W2h[32K,64K) staged once; bounce 8KB/wave at [64K+).
// x loaded at tile start (no cross-tile raw[] -> no spills); fp16 RNE everywhere;
// MFMA order k-outer/cf-inner for 16-deep independent accumulator stream.
__global__ __launch_bounds__(512, 2) void mlp_gemm(
    const float* __restrict__ x, const unsigned short* __restrict__ wt,
    const int* __restrict__ perm, const int* __restrict__ offs,
    const float* __restrict__ b1, const float* __restrict__ b2,
    const float* __restrict__ W3, const float* __restrict__ b3,
    const float* __restrict__ slope, const float* __restrict__ intercept,
    float* __restrict__ e_atom) {
  extern __shared__ char lds[];  // 128 KB

  int s = blockIdx.x >> 6;
  int kblk = blockIdx.x & 63;
  int base = offs[s];
  int T = (offs[s + 1] - base) >> 8;

  int tid = threadIdx.x;
  int wave = tid >> 6, lane = tid & 63;
  int r0 = lane & 15, chunk = lane >> 4;
  char* bounce = lds + 65536 + wave * 8192;

  const unsigned short* w1p = wt + (size_t)(0 + s) * 16384;
  const unsigned short* w2p = wt + (size_t)(4 + s) * 16384;

  // ---- stage W1h+W2h once: 4096 x 16B granules, async DMA, linear dest ----
#pragma unroll
  for (int it = 0; it < 8; ++it) {
    int gb = it * 512 + wave * 64;
    const unsigned short* src = (gb >= 2048) ? (w2p + (size_t)(gb - 2048 + lane) * 8)
                                             : (w1p + (size_t)(gb + lane) * 8);
    __builtin_amdgcn_global_load_lds((const unsigned int*)src,
                                     (unsigned int*)(lds + (size_t)gb * 16), 16, 0, 0);
  }

  // ---- hoist per-symbol constants ----
  float b1v[8], b2v[8], w3v[8];
#pragma unroll
  for (int cf = 0; cf < 8; ++cf) {
    b1v[cf] = b1[s * 128 + cf * 16 + r0];
    b2v[cf] = b2[s * 128 + cf * 16 + r0];
    w3v[cf] = W3[s * 128 + cf * 16 + r0];
  }
  float sl = slope[s], ic = intercept[s], bb = b3[s];

  __syncthreads();  // W staged

  f32x4 zero4 = {0.f, 0.f, 0.f, 0.f};

  for (int t = kblk; t < T; t += 64) {
    // ---- x load + fp16 RNE convert -> ah[8] (frag f = rf*4 + kk) ----
    int a0 = perm[base + (t << 8) + wave * 32 + r0];
    int a1 = perm[base + (t << 8) + wave * 32 + 16 + r0];
    f16x8 ah[8];
#pragma unroll
    for (int rf = 0; rf < 2; ++rf) {
      int atom = rf ? a1 : a0;
      const float* xr = x + (long)(atom < 0 ? 0 : atom) * 128;  // pad lanes: row 0, never stored
#pragma unroll
      for (int kk = 0; kk < 4; ++kk) {
        float4 v0 = *(const float4*)(xr + kk * 32 + chunk * 8);
        float4 v1 = *(const float4*)(xr + kk * 32 + chunk * 8 + 4);
        f16x8 f;
        f[0] = (_Float16)v0.x; f[1] = (_Float16)v0.y;
        f[2] = (_Float16)v0.z; f[3] = (_Float16)v0.w;
        f[4] = (_Float16)v1.x; f[5] = (_Float16)v1.y;
        f[6] = (_Float16)v1.z; f[7] = (_Float16)v1.w;
        ah[rf * 4 + kk] = f;
      }
    }

    // ---- layer 1: acc = x * W1h, k-outer / cf-inner ----
    f32x4 acc[2][8];
#pragma unroll
    for (int i = 0; i < 2; ++i)
#pragma unroll
      for (int j = 0; j < 8; ++j) acc[i][j] = zero4;

#pragma unroll
    for (int k = 0; k < 4; ++k)
#pragma unroll
      for (int cf = 0; cf < 8; ++cf) {
        int row = cf * 16 + r0;
        f16x8 bh = *(const f16x8*)(lds + row * 256 +
                                   ((((k * 4 + chunk)) << 4) ^ ((row & 7) << 4)));
        acc[0][cf] = __builtin_amdgcn_mfma_f32_16x16x32_f16(ah[k], bh, acc[0][cf], 0, 0, 0);
        acc[1][cf] = __builtin_amdgcn_mfma_f32_16x16x32_f16(ah[4 + k], bh, acc[1][cf], 0, 0, 0);
      }

    // ---- bounce: h1 = relu(acc+b1) -> fp16 (dup-packed u32), 2 half-passes ----
#pragma unroll
    for (int hp2 = 0; hp2 < 2; ++hp2) {
#pragma unroll
      for (int cf4 = 0; cf4 < 4; ++cf4) {
        int cf = hp2 * 4 + cf4;
        float bias = b1v[cf];
        int colp = cf4 * 16 + r0;
#pragma unroll
        for (int rf = 0; rf < 2; ++rf)
#pragma unroll
          for (int rr = 0; rr < 4; ++rr) {
            int row = rf * 16 + chunk * 4 + rr;
            float v = fmaxf(acc[rf][cf][rr] + bias, 0.f);
            unsigned short h = __builtin_bit_cast(unsigned short, (_Float16)v);  // RNE
            int cc = colp ^ (chunk << 4) ^ (rr << 2);
            *(unsigned int*)(bounce + row * 256 + cc * 4) = ((unsigned int)h << 16) | h;
          }
      }
      // read back frags kk = hp2*2, hp2*2+1 into ah (h1 hi halves only)
#pragma unroll
      for (int kk2 = 0; kk2 < 2; ++kk2) {
        int kk = hp2 * 2 + kk2;
#pragma unroll
        for (int rf = 0; rf < 2; ++rf) {
          int row = rf * 16 + r0;
          int xr3 = ((r0 >> 2) << 4) ^ ((r0 & 3) << 2);
          int c0 = kk2 * 32 + chunk * 8;
          u32x4 pa = *(const u32x4*)(bounce + row * 256 + (c0 ^ xr3) * 4);
          u32x4 pb = *(const u32x4*)(bounce + row * 256 + ((c0 + 4) ^ xr3) * 4);
          unsigned int h01 = (pa[0] >> 16) | (pa[1] & 0xffff0000u);
          unsigned int h23 = (pa[2] >> 16) | (pa[3] & 0xffff0000u);
          unsigned int h45 = (pb[0] >> 16) | (pb[1] & 0xffff0000u);
          unsigned int h67 = (pb[2] >> 16) | (pb[3] & 0xffff0000u);
          u32x4 hq = {h01, h23, h45, h67};
          ah[rf * 4 + kk] = __builtin_bit_cast(f16x8, hq);
        }
      }
    }

    // ---- layer 2: acc = h1 * W2h, k-outer / cf-inner ----
#pragma unroll
    for (int i = 0; i < 2; ++i)
#pragma unroll
      for (int j = 0; j < 8; ++j) acc[i][j] = zero4;

#pragma unroll
    for (int k = 0; k < 4; ++k)
#pragma unroll
      for (int cf = 0; cf < 8; ++cf) {
        int row = cf * 16 + r0;
        f16x8 bh = *(const f16x8*)(lds + 32768 + row * 256 +
                                   ((((k * 4 + chunk)) << 4) ^ ((row & 7) << 4)));
        acc[0][cf] = __builtin_amdgcn_mfma_f32_16x16x32_f16(ah[k], bh, acc[0][cf], 0, 0, 0);
        acc[1][cf] = __builtin_amdgcn_mfma_f32_16x16x32_f16(ah[4 + k], bh, acc[1][cf], 0, 0, 0);
      }

    // ---- epilogue: e = relu(acc+b2).W3, affine, scatter ----
    float p[2][4] = {{0.f, 0.f, 0.f, 0.f}, {0.f, 0.f, 0.f, 0.f}};
#pragma unroll
    for (int cf = 0; cf < 8; ++cf)
#pragma unroll
      for (int rf = 0; rf < 2; ++rf)
#pragma unroll
        for (int rr = 0; rr < 4; ++rr)
          p[rf][rr] += fmaxf(acc[rf][cf][rr] + b2v[cf], 0.f) * w3v[cf];
#pragma unroll
    for (int m = 1; m < 16; m <<= 1)
#pragma unroll
      for (int rf = 0; rf < 2; ++rf)
#pragma unroll
        for (int rr = 0; rr < 4; ++rr) p[rf][rr] += __shfl_xor(p[rf][rr], m);

    if (r0 == 0) {
#pragma unroll
      for (int rf = 0; rf < 2; ++rf)
#pragma unroll
        for (int rr = 0; rr < 4; ++rr) {
          int row = wave * 32 + rf * 16 + chunk * 4 + rr;
          int a = perm[base + (t << 8) + row];
          if (a >= 0) e_atom[a] = sl * (p[rf][rr] + bb) + ic;
        }
    }
  }
}

// ---------- kernel 6: deterministic per-image segment sum ----------
__global__ void segsum_kernel(const float* __restrict__ e_atom, const int* __restrict__ img,
                              float* __restrict__ out, int n) {
  int b = blockIdx.x;
  int lo = 0, hi = n;
  while (lo < hi) { int m = (lo + hi) >> 1; if (img[m] < b) lo = m + 1; else hi = m; }
  int lo2 = lo, hi2 = n;
  while (lo2 < hi2) { int m = (lo2 + hi2) >> 1; if (img[m] < b + 1) lo2 = m + 1; else hi2 = m; }
  float sum = 0.f;
  for (int i = lo + threadIdx.x; i < lo2; i += blockDim.x) sum += e_atom[i];
  for (int m = 32; m; m >>= 1) sum += __shfl_down(sum, m);
  __shared__ float part[4];
  int lane = threadIdx.x & 63, wave = threadIdx.x >> 6;
  if (lane == 0) part[wave] = sum;
  __syncthreads();
  if (threadIdx.x == 0) out[b] = part[0] + part[1] + part[2] + part[3];
}

extern "C" void kernel_launch(void* const* d_in, const int* in_sizes, int n_in,
                              void* d_out, int out_size, void* d_ws, size_t ws_size,
                              hipStream_t stream) {
  const float* x         = (const float*)d_in[0];
  const float* W1        = (const float*)d_in[1];
  const float* b1        = (const float*)d_in[2];
  const float* W2        = (const float*)d_in[3];
  const float* b2        = (const float*)d_in[4];
  const float* W3        = (const float*)d_in[5];
  const float* b3        = (const float*)d_in[6];
  const float* slope     = (const float*)d_in[7];
  const float* intercept = (const float*)d_in[8];
  const int* sym         = (const int*)d_in[9];
  const int* img         = (const int*)d_in[10];

  char* ws = (char*)d_ws;
  int* wbh    = (int*)ws;                          // 16384 B
  int* bases  = (int*)(ws + 16384);                // 16384 B
  int* offs   = (int*)(ws + 32768);                // 64 B
  int* perm   = (int*)(ws + 32832);                // (N+1024)*4
  float* e_atom = (float*)(ws + 32832 + 1052672);  // N*4
  unsigned short* wt = (unsigned short*)(ws + 32832 + 1052672 + 1048576);  // 256 KB

  hist_kernel<<<1024, 256, 0, stream>>>(sym, wbh);
  offsets_kernel<<<1, 256, 0, stream>>>(wbh, bases, offs, perm);
  scatter_kernel<<<1024, 256, 0, stream>>>(sym, bases, perm);
  wconv_kernel<<<512, 256, 0, stream>>>(W1, W2, wt);
  mlp_gemm<<<256, 512, 131072, stream>>>(x, wt, perm, offs, b1, b2,
                                         W3, b3, slope, intercept, e_atom);
  segsum_kernel<<<NIMG, 256, 0, stream>>>(e_atom, img, (float*)d_out, N_ATOMS);
}